// Round 1
// baseline (2696.969 us; speedup 1.0000x reference)
//
#include <hip/hip_runtime.h>

// ---------------------------------------------------------------------------
// DGL GAT (2-layer, heads=4, out=32) + WeightedSumAndMax readout, f32.
// Round 0: correctness-first pipeline with atomic-scatter edge softmax.
// ---------------------------------------------------------------------------

#define HEADS 4
#define OUTF 32
#define HF 128            // HEADS*OUTF
#define IN_FEATS 74
#define PRED_DIM 128
#define NEG_SLOPE 0.2f
#define NEG_INF_ENC 0x007fffffu   // enc_f(-inf)

__device__ __forceinline__ unsigned enc_f(float f) {
  unsigned u = __float_as_uint(f);
  return (u & 0x80000000u) ? ~u : (u | 0x80000000u);
}
__device__ __forceinline__ float dec_f(unsigned k) {
  return (k & 0x80000000u) ? __uint_as_float(k & 0x7fffffffu)
                           : __uint_as_float(~k);
}

// out[n][j] = dot(X[n, :K], W[:K, j]),  j in [0,128). 2 nodes / 256-thr block.
template <int K>
__global__ __launch_bounds__(256) void gemm_node(
    const float* __restrict__ X, const float* __restrict__ W,
    float* __restrict__ out, int N) {
  __shared__ float Ws[K * HF];
  for (int i = threadIdx.x; i < K * HF; i += 256) Ws[i] = W[i];
  __syncthreads();
  int n = blockIdx.x * 2 + (threadIdx.x >> 7);
  int j = threadIdx.x & 127;
  if (n >= N) return;
  const float* x = X + (size_t)n * K;
  float acc = 0.f;
#pragma unroll 2
  for (int k = 0; k < K; ++k) acc = fmaf(x[k], Ws[k * HF + j], acc);
  out[(size_t)n * HF + j] = acc;
}

// el[n][h] = dot(feat[n][h], attn_l[h]); er likewise. 1 thread / (n,h).
__global__ __launch_bounds__(256) void scores_kernel(
    const float* __restrict__ feat, const float* __restrict__ attn_l,
    const float* __restrict__ attn_r, float* __restrict__ el,
    float* __restrict__ er, int N) {
  int t = blockIdx.x * 256 + threadIdx.x;  // t = n*4 + h
  if (t >= N * HEADS) return;
  int h = t & 3;
  const float* f = feat + (size_t)t * OUTF;  // == feat[n*128 + h*32]
  const float* al = attn_l + h * OUTF;
  const float* ar = attn_r + h * OUTF;
  float sl = 0.f, sr = 0.f;
#pragma unroll
  for (int k = 0; k < OUTF; ++k) {
    float v = f[k];
    sl = fmaf(v, al[k], sl);
    sr = fmaf(v, ar[k], sr);
  }
  el[t] = sl;
  er[t] = sr;
}

__global__ __launch_bounds__(256) void init_softmax_kernel(
    unsigned* __restrict__ emax, float* __restrict__ denom, int n4) {
  int t = blockIdx.x * 256 + threadIdx.x;
  if (t >= n4) return;
  emax[t] = NEG_INF_ENC;
  denom[t] = 0.f;
}

__global__ __launch_bounds__(256) void edge_max_kernel(
    const int* __restrict__ src, const int* __restrict__ dst,
    const float* __restrict__ el, const float* __restrict__ er,
    unsigned* __restrict__ emax, int E) {
  int t = blockIdx.x * 256 + threadIdx.x;  // t = e*4 + h
  if (t >= E * HEADS) return;
  int e = t >> 2, h = t & 3;
  int s = src[e], d = dst[e];
  float v = el[s * HEADS + h] + er[d * HEADS + h];
  v = (v >= 0.f) ? v : NEG_SLOPE * v;
  atomicMax(&emax[d * HEADS + h], enc_f(v));
}

__global__ __launch_bounds__(256) void edge_exp_kernel(
    const int* __restrict__ src, const int* __restrict__ dst,
    const float* __restrict__ el, const float* __restrict__ er,
    const unsigned* __restrict__ emax, float* __restrict__ ee,
    float* __restrict__ denom, int E) {
  int t = blockIdx.x * 256 + threadIdx.x;
  if (t >= E * HEADS) return;
  int e = t >> 2, h = t & 3;
  int s = src[e], d = dst[e];
  float v = el[s * HEADS + h] + er[d * HEADS + h];
  v = (v >= 0.f) ? v : NEG_SLOPE * v;
  float m = dec_f(emax[d * HEADS + h]);
  float x = expf(v - m);
  ee[t] = x;
  atomicAdd(&denom[d * HEADS + h], x);
}

// rst[dst][j] += ee[e][h] * feat[src][j]   (j = h*32+f), unnormalized.
__global__ __launch_bounds__(256) void edge_agg_kernel(
    const int* __restrict__ src, const int* __restrict__ dst,
    const float* __restrict__ ee, const float* __restrict__ feat,
    float* __restrict__ rst, int E) {
  int t = blockIdx.x * 256 + threadIdx.x;  // t = e*128 + j
  if (t >= E * HF) return;
  int e = t >> 7, j = t & 127, h = j >> 5;
  int s = src[e], d = dst[e];
  float v = ee[e * HEADS + h] * feat[(size_t)s * HF + j];
  atomicAdd(&rst[(size_t)d * HF + j], v);
}

// h1[n][j] = elu(rst[n][j]/denom[n][h] + res[n][j] + bias[j]); in-place on res.
__global__ __launch_bounds__(256) void finalize1_kernel(
    float* __restrict__ h1io, const float* __restrict__ rst,
    const float* __restrict__ denom, const float* __restrict__ bias, int N) {
  int t = blockIdx.x * 256 + threadIdx.x;  // t = n*128 + j
  if (t >= N * HF) return;
  int n = t >> 7, j = t & 127, h = j >> 5;
  float v = rst[t] / denom[n * HEADS + h] + h1io[t] + bias[j];
  h1io[t] = (v > 0.f) ? v : expm1f(v);
}

// nf[n][f] = mean_h( rst[n][h][f]/denom[n][h] + h1[n][h][f] + bias[h][f] )
__global__ __launch_bounds__(256) void finalize2_kernel(
    float* __restrict__ nf, const float* __restrict__ rst,
    const float* __restrict__ denom, const float* __restrict__ h1,
    const float* __restrict__ bias, int N) {
  int t = blockIdx.x * 256 + threadIdx.x;  // t = n*32 + f
  if (t >= N * OUTF) return;
  int n = t >> 5, f = t & 31;
  float s = 0.f;
#pragma unroll
  for (int h = 0; h < HEADS; ++h) {
    int j = h * OUTF + f;
    s += rst[(size_t)n * HF + j] / denom[n * HEADS + h] +
         h1[(size_t)n * HF + j] + bias[j];
  }
  nf[t] = 0.25f * s;
}

__global__ __launch_bounds__(256) void node_w_kernel(
    const float* __restrict__ nf, const float* __restrict__ ww,
    const float* __restrict__ wb, float* __restrict__ w, int N) {
  int n = blockIdx.x * 256 + threadIdx.x;
  if (n >= N) return;
  float s = wb[0];
  const float* x = nf + (size_t)n * OUTF;
#pragma unroll
  for (int k = 0; k < OUTF; ++k) s = fmaf(x[k], ww[k], s);
  w[n] = 1.f / (1.f + expf(-s));
}

__global__ __launch_bounds__(256) void init_readout_kernel(
    unsigned* __restrict__ hmax, int g32) {
  int t = blockIdx.x * 256 + threadIdx.x;
  if (t >= g32) return;
  hmax[t] = NEG_INF_ENC;
}

__global__ __launch_bounds__(256) void readout_kernel(
    const float* __restrict__ nf, const float* __restrict__ w,
    const int* __restrict__ gids, float* __restrict__ hsum,
    unsigned* __restrict__ hmax, int N) {
  int t = blockIdx.x * 256 + threadIdx.x;  // t = n*32 + f
  if (t >= N * OUTF) return;
  int n = t >> 5, f = t & 31;
  int g = gids[n];
  float v = nf[t];
  atomicAdd(&hsum[g * OUTF + f], w[n] * v);
  atomicMax(&hmax[g * OUTF + f], enc_f(v));
}

// out[g][p] = tb[p] + sum_k hsum[g][k]*tw[k][p] + sum_k hmax[g][k]*tw[32+k][p]
__global__ __launch_bounds__(256) void final_gemm_kernel(
    const float* __restrict__ hsum, const unsigned* __restrict__ hmax,
    const float* __restrict__ tw, const float* __restrict__ tb,
    float* __restrict__ out, int G) {
  __shared__ float tws[64 * PRED_DIM];
  for (int i = threadIdx.x; i < 64 * PRED_DIM; i += 256) tws[i] = tw[i];
  __syncthreads();
  int g = blockIdx.x * 2 + (threadIdx.x >> 7);
  int p = threadIdx.x & 127;
  if (g >= G) return;
  float acc = tb[p];
#pragma unroll
  for (int k = 0; k < OUTF; ++k)
    acc = fmaf(hsum[g * OUTF + k], tws[k * PRED_DIM + p], acc);
#pragma unroll
  for (int k = 0; k < OUTF; ++k)
    acc = fmaf(dec_f(hmax[g * OUTF + k]), tws[(OUTF + k) * PRED_DIM + p], acc);
  out[(size_t)g * PRED_DIM + p] = acc;
}

static inline int cdiv(long long a, int b) { return (int)((a + b - 1) / b); }

extern "C" void kernel_launch(void* const* d_in, const int* in_sizes, int n_in,
                              void* d_out, int out_size, void* d_ws,
                              size_t ws_size, hipStream_t stream) {
  const float* feats   = (const float*)d_in[0];
  const int*   src     = (const int*)d_in[1];
  const int*   dst     = (const int*)d_in[2];
  const int*   gids    = (const int*)d_in[3];
  const float* fc1_w   = (const float*)d_in[4];
  const float* attn_l1 = (const float*)d_in[5];
  const float* attn_r1 = (const float*)d_in[6];
  const float* res1_w  = (const float*)d_in[7];
  const float* bias1   = (const float*)d_in[8];
  const float* fc2_w   = (const float*)d_in[9];
  const float* attn_l2 = (const float*)d_in[10];
  const float* attn_r2 = (const float*)d_in[11];
  const float* bias2   = (const float*)d_in[12];
  const float* ww      = (const float*)d_in[13];
  const float* wb      = (const float*)d_in[14];
  const float* tw      = (const float*)d_in[15];
  const float* tb      = (const float*)d_in[16];
  float* out = (float*)d_out;

  const int N = in_sizes[0] / IN_FEATS;  // 100000
  const int E = in_sizes[1];             // 900000
  const int G = out_size / PRED_DIM;     // 2048

  // ---- workspace layout (f32 elements) ----
  float* A  = (float*)d_ws;            // N*128  feat1 / feat2 / (later) node_feats
  float* B  = A + (size_t)N * HF;      // N*128  res1 -> h1 (in place)
  float* C  = B + (size_t)N * HF;      // N*128  aggregate accumulator
  float* ee = C + (size_t)N * HF;      // E*4    per-edge exp values
  float* el = ee + (size_t)E * HEADS;  // N*4
  float* er = el + (size_t)N * HEADS;  // N*4
  unsigned* emax = (unsigned*)(er + (size_t)N * HEADS);  // N*4
  float* denom = (float*)(emax + (size_t)N * HEADS);     // N*4
  // reuse after layer-2 edge_exp:
  float* nf = A;            // N*32 node feats
  float* w  = el;           // N    sigmoid gates
  float* hsum = er;         // G*32
  unsigned* hmax = emax;    // G*32

  const int n4 = N * HEADS;
  const int e4 = E * HEADS;

  // ===================== Layer 1 =====================
  gemm_node<IN_FEATS><<<cdiv(N, 2), 256, 0, stream>>>(feats, fc1_w, A, N);
  gemm_node<IN_FEATS><<<cdiv(N, 2), 256, 0, stream>>>(feats, res1_w, B, N);
  scores_kernel<<<cdiv(n4, 256), 256, 0, stream>>>(A, attn_l1, attn_r1, el, er, N);
  init_softmax_kernel<<<cdiv(n4, 256), 256, 0, stream>>>(emax, denom, n4);
  hipMemsetAsync(C, 0, (size_t)N * HF * sizeof(float), stream);
  edge_max_kernel<<<cdiv(e4, 256), 256, 0, stream>>>(src, dst, el, er, emax, E);
  edge_exp_kernel<<<cdiv(e4, 256), 256, 0, stream>>>(src, dst, el, er, emax, ee, denom, E);
  edge_agg_kernel<<<cdiv((long long)E * HF, 256), 256, 0, stream>>>(src, dst, ee, A, C, E);
  finalize1_kernel<<<cdiv((long long)N * HF, 256), 256, 0, stream>>>(B, C, denom, bias1, N);

  // ===================== Layer 2 =====================
  gemm_node<HF><<<cdiv(N, 2), 256, 0, stream>>>(B, fc2_w, A, N);
  scores_kernel<<<cdiv(n4, 256), 256, 0, stream>>>(A, attn_l2, attn_r2, el, er, N);
  init_softmax_kernel<<<cdiv(n4, 256), 256, 0, stream>>>(emax, denom, n4);
  hipMemsetAsync(C, 0, (size_t)N * HF * sizeof(float), stream);
  edge_max_kernel<<<cdiv(e4, 256), 256, 0, stream>>>(src, dst, el, er, emax, E);
  edge_exp_kernel<<<cdiv(e4, 256), 256, 0, stream>>>(src, dst, el, er, emax, ee, denom, E);
  edge_agg_kernel<<<cdiv((long long)E * HF, 256), 256, 0, stream>>>(src, dst, ee, A, C, E);
  finalize2_kernel<<<cdiv((long long)N * OUTF, 256), 256, 0, stream>>>(nf, C, denom, B, bias2, N);

  // ===================== Readout =====================
  node_w_kernel<<<cdiv(N, 256), 256, 0, stream>>>(nf, ww, wb, w, N);
  hipMemsetAsync(hsum, 0, (size_t)G * OUTF * sizeof(float), stream);
  init_readout_kernel<<<cdiv(G * OUTF, 256), 256, 0, stream>>>(hmax, G * OUTF);
  readout_kernel<<<cdiv((long long)N * OUTF, 256), 256, 0, stream>>>(nf, w, gids, hsum, hmax, N);
  final_gemm_kernel<<<cdiv(G, 2), 256, 0, stream>>>(hsum, hmax, tw, tb, out, G);
}

// Round 2
// 1333.737 us; speedup vs baseline: 2.0221x; 2.0221x over previous
//
#include <hip/hip_runtime.h>

// ---------------------------------------------------------------------------
// DGL GAT (2-layer, heads=4, out=32) + WeightedSumAndMax readout, f32.
// Round 1: register-tiled node GEMM (64x128 block tile, 8x4 micro-tile);
//          edge_max caches leaky-relu value for edge_exp.
// ---------------------------------------------------------------------------

#define HEADS 4
#define OUTF 32
#define HF 128            // HEADS*OUTF
#define IN_FEATS 74
#define PRED_DIM 128
#define NEG_SLOPE 0.2f
#define NEG_INF_ENC 0x007fffffu   // enc_f(-inf)

__device__ __forceinline__ unsigned enc_f(float f) {
  unsigned u = __float_as_uint(f);
  return (u & 0x80000000u) ? ~u : (u | 0x80000000u);
}
__device__ __forceinline__ float dec_f(unsigned k) {
  return (k & 0x80000000u) ? __uint_as_float(k & 0x7fffffffu)
                           : __uint_as_float(~k);
}

// out[n][j] = dot(X[n,:K], W[:K,j]). Block: 64 nodes x 128 cols, 256 thr,
// 8 nodes x 4 cols per thread. A staged transposed as[kk][node] (pad 68),
// B staged bs[kk][col]. Inner loop: 3 ds_read_b128 per 32 FMAs.
template <int K>
__global__ __launch_bounds__(256) void gemm_tiled(
    const float* __restrict__ X, const float* __restrict__ W,
    float* __restrict__ out, int N) {
  constexpr int BK = 32;
  constexpr int APAD = 68;  // 64 + 4: 16B-aligned rows, conflict-light
  __shared__ float as[BK * APAD];
  __shared__ float bs[BK * HF];
  const int tid = threadIdx.x;
  const int tx = tid & 31;   // col group: cols j4..j4+3
  const int ty = tid >> 5;   // node group: nodes nb..nb+7
  const int j4 = tx * 4;
  const int nb = ty * 8;
  const int n0 = blockIdx.x * 64;

  float acc[8][4] = {};
  for (int k0 = 0; k0 < K; k0 += BK) {
    // stage A tile (64 x BK), transposed into as[kk][node]
#pragma unroll
    for (int i = 0; i < 8; ++i) {
      int idx = i * 256 + tid;           // 0..2047
      int kk = idx & 31, nl = idx >> 5;
      int n = n0 + nl, k = k0 + kk;
      float v = 0.f;
      if (n < N && k < K) v = X[(size_t)n * K + k];
      as[kk * APAD + nl] = v;
    }
    // stage B tile (BK x 128)
#pragma unroll
    for (int i = 0; i < 16; ++i) {
      int idx = i * 256 + tid;           // 0..4095
      int kk = idx >> 7, c = idx & 127;
      int k = k0 + kk;
      bs[idx] = (k < K) ? W[(size_t)k * HF + c] : 0.f;
    }
    __syncthreads();
#pragma unroll 8
    for (int kk = 0; kk < BK; ++kk) {
      float4 wv = *(const float4*)&bs[kk * HF + j4];
      float4 a0 = *(const float4*)&as[kk * APAD + nb];
      float4 a1 = *(const float4*)&as[kk * APAD + nb + 4];
      float av[8] = {a0.x, a0.y, a0.z, a0.w, a1.x, a1.y, a1.z, a1.w};
#pragma unroll
      for (int i = 0; i < 8; ++i) {
        acc[i][0] = fmaf(av[i], wv.x, acc[i][0]);
        acc[i][1] = fmaf(av[i], wv.y, acc[i][1]);
        acc[i][2] = fmaf(av[i], wv.z, acc[i][2]);
        acc[i][3] = fmaf(av[i], wv.w, acc[i][3]);
      }
    }
    __syncthreads();
  }
#pragma unroll
  for (int i = 0; i < 8; ++i) {
    int n = n0 + nb + i;
    if (n < N)
      *(float4*)&out[(size_t)n * HF + j4] =
          make_float4(acc[i][0], acc[i][1], acc[i][2], acc[i][3]);
  }
}

// el[n][h] = dot(feat[n][h], attn_l[h]); er likewise. 1 thread / (n,h).
__global__ __launch_bounds__(256) void scores_kernel(
    const float* __restrict__ feat, const float* __restrict__ attn_l,
    const float* __restrict__ attn_r, float* __restrict__ el,
    float* __restrict__ er, int N) {
  int t = blockIdx.x * 256 + threadIdx.x;  // t = n*4 + h
  if (t >= N * HEADS) return;
  int h = t & 3;
  const float* f = feat + (size_t)t * OUTF;
  const float* al = attn_l + h * OUTF;
  const float* ar = attn_r + h * OUTF;
  float sl = 0.f, sr = 0.f;
#pragma unroll
  for (int k = 0; k < OUTF; ++k) {
    float v = f[k];
    sl = fmaf(v, al[k], sl);
    sr = fmaf(v, ar[k], sr);
  }
  el[t] = sl;
  er[t] = sr;
}

__global__ __launch_bounds__(256) void init_softmax_kernel(
    unsigned* __restrict__ emax, float* __restrict__ denom, int n4) {
  int t = blockIdx.x * 256 + threadIdx.x;
  if (t >= n4) return;
  emax[t] = NEG_INF_ENC;
  denom[t] = 0.f;
}

// computes leaky-relu edge value, caches it to ee, atomicMax into emax
__global__ __launch_bounds__(256) void edge_max_kernel(
    const int* __restrict__ src, const int* __restrict__ dst,
    const float* __restrict__ el, const float* __restrict__ er,
    unsigned* __restrict__ emax, float* __restrict__ ee, int E) {
  int t = blockIdx.x * 256 + threadIdx.x;  // t = e*4 + h
  if (t >= E * HEADS) return;
  int e = t >> 2, h = t & 3;
  int s = src[e], d = dst[e];
  float v = el[s * HEADS + h] + er[d * HEADS + h];
  v = (v >= 0.f) ? v : NEG_SLOPE * v;
  ee[t] = v;
  atomicMax(&emax[d * HEADS + h], enc_f(v));
}

// reads cached v from ee, writes exp back to ee, atomicAdd into denom
__global__ __launch_bounds__(256) void edge_exp_kernel(
    const int* __restrict__ dst, const unsigned* __restrict__ emax,
    float* __restrict__ ee, float* __restrict__ denom, int E) {
  int t = blockIdx.x * 256 + threadIdx.x;
  if (t >= E * HEADS) return;
  int e = t >> 2, h = t & 3;
  int d = dst[e];
  float m = dec_f(emax[d * HEADS + h]);
  float x = expf(ee[t] - m);
  ee[t] = x;
  atomicAdd(&denom[d * HEADS + h], x);
}

// rst[dst][j] += ee[e][h] * feat[src][j]   (j = h*32+f), unnormalized.
__global__ __launch_bounds__(256) void edge_agg_kernel(
    const int* __restrict__ src, const int* __restrict__ dst,
    const float* __restrict__ ee, const float* __restrict__ feat,
    float* __restrict__ rst, int E) {
  int t = blockIdx.x * 256 + threadIdx.x;  // t = e*128 + j
  if (t >= E * HF) return;
  int e = t >> 7, j = t & 127, h = j >> 5;
  int s = src[e], d = dst[e];
  float v = ee[e * HEADS + h] * feat[(size_t)s * HF + j];
  atomicAdd(&rst[(size_t)d * HF + j], v);
}

// h1[n][j] = elu(rst[n][j]/denom[n][h] + res[n][j] + bias[j]); in-place on res.
__global__ __launch_bounds__(256) void finalize1_kernel(
    float* __restrict__ h1io, const float* __restrict__ rst,
    const float* __restrict__ denom, const float* __restrict__ bias, int N) {
  int t = blockIdx.x * 256 + threadIdx.x;  // t = n*128 + j
  if (t >= N * HF) return;
  int n = t >> 7, j = t & 127, h = j >> 5;
  float v = rst[t] / denom[n * HEADS + h] + h1io[t] + bias[j];
  h1io[t] = (v > 0.f) ? v : expm1f(v);
}

// nf[n][f] = mean_h( rst[n][h][f]/denom[n][h] + h1[n][h][f] + bias[h][f] )
__global__ __launch_bounds__(256) void finalize2_kernel(
    float* __restrict__ nf, const float* __restrict__ rst,
    const float* __restrict__ denom, const float* __restrict__ h1,
    const float* __restrict__ bias, int N) {
  int t = blockIdx.x * 256 + threadIdx.x;  // t = n*32 + f
  if (t >= N * OUTF) return;
  int n = t >> 5, f = t & 31;
  float s = 0.f;
#pragma unroll
  for (int h = 0; h < HEADS; ++h) {
    int j = h * OUTF + f;
    s += rst[(size_t)n * HF + j] / denom[n * HEADS + h] +
         h1[(size_t)n * HF + j] + bias[j];
  }
  nf[t] = 0.25f * s;
}

__global__ __launch_bounds__(256) void node_w_kernel(
    const float* __restrict__ nf, const float* __restrict__ ww,
    const float* __restrict__ wb, float* __restrict__ w, int N) {
  int n = blockIdx.x * 256 + threadIdx.x;
  if (n >= N) return;
  float s = wb[0];
  const float* x = nf + (size_t)n * OUTF;
#pragma unroll
  for (int k = 0; k < OUTF; ++k) s = fmaf(x[k], ww[k], s);
  w[n] = 1.f / (1.f + expf(-s));
}

__global__ __launch_bounds__(256) void init_readout_kernel(
    unsigned* __restrict__ hmax, int g32) {
  int t = blockIdx.x * 256 + threadIdx.x;
  if (t >= g32) return;
  hmax[t] = NEG_INF_ENC;
}

__global__ __launch_bounds__(256) void readout_kernel(
    const float* __restrict__ nf, const float* __restrict__ w,
    const int* __restrict__ gids, float* __restrict__ hsum,
    unsigned* __restrict__ hmax, int N) {
  int t = blockIdx.x * 256 + threadIdx.x;  // t = n*32 + f
  if (t >= N * OUTF) return;
  int n = t >> 5, f = t & 31;
  int g = gids[n];
  float v = nf[t];
  atomicAdd(&hsum[g * OUTF + f], w[n] * v);
  atomicMax(&hmax[g * OUTF + f], enc_f(v));
}

// out[g][p] = tb[p] + sum_k hsum[g][k]*tw[k][p] + sum_k hmax[g][k]*tw[32+k][p]
__global__ __launch_bounds__(256) void final_gemm_kernel(
    const float* __restrict__ hsum, const unsigned* __restrict__ hmax,
    const float* __restrict__ tw, const float* __restrict__ tb,
    float* __restrict__ out, int G) {
  __shared__ float tws[64 * PRED_DIM];
  for (int i = threadIdx.x; i < 64 * PRED_DIM; i += 256) tws[i] = tw[i];
  __syncthreads();
  int g = blockIdx.x * 2 + (threadIdx.x >> 7);
  int p = threadIdx.x & 127;
  if (g >= G) return;
  float acc = tb[p];
#pragma unroll
  for (int k = 0; k < OUTF; ++k)
    acc = fmaf(hsum[g * OUTF + k], tws[k * PRED_DIM + p], acc);
#pragma unroll
  for (int k = 0; k < OUTF; ++k)
    acc = fmaf(dec_f(hmax[g * OUTF + k]), tws[(OUTF + k) * PRED_DIM + p], acc);
  out[(size_t)g * PRED_DIM + p] = acc;
}

static inline int cdiv(long long a, int b) { return (int)((a + b - 1) / b); }

extern "C" void kernel_launch(void* const* d_in, const int* in_sizes, int n_in,
                              void* d_out, int out_size, void* d_ws,
                              size_t ws_size, hipStream_t stream) {
  const float* feats   = (const float*)d_in[0];
  const int*   src     = (const int*)d_in[1];
  const int*   dst     = (const int*)d_in[2];
  const int*   gids    = (const int*)d_in[3];
  const float* fc1_w   = (const float*)d_in[4];
  const float* attn_l1 = (const float*)d_in[5];
  const float* attn_r1 = (const float*)d_in[6];
  const float* res1_w  = (const float*)d_in[7];
  const float* bias1   = (const float*)d_in[8];
  const float* fc2_w   = (const float*)d_in[9];
  const float* attn_l2 = (const float*)d_in[10];
  const float* attn_r2 = (const float*)d_in[11];
  const float* bias2   = (const float*)d_in[12];
  const float* ww      = (const float*)d_in[13];
  const float* wb      = (const float*)d_in[14];
  const float* tw      = (const float*)d_in[15];
  const float* tb      = (const float*)d_in[16];
  float* out = (float*)d_out;

  const int N = in_sizes[0] / IN_FEATS;  // 100000
  const int E = in_sizes[1];             // 900000
  const int G = out_size / PRED_DIM;     // 2048

  // ---- workspace layout (f32 elements) ----
  float* A  = (float*)d_ws;            // N*128  feat1 / feat2 / node_feats
  float* B  = A + (size_t)N * HF;      // N*128  res1 -> h1 (in place)
  float* C  = B + (size_t)N * HF;      // N*128  aggregate accumulator
  float* ee = C + (size_t)N * HF;      // E*4    per-edge leaky / exp values
  float* el = ee + (size_t)E * HEADS;  // N*4
  float* er = el + (size_t)N * HEADS;  // N*4
  unsigned* emax = (unsigned*)(er + (size_t)N * HEADS);  // N*4
  float* denom = (float*)(emax + (size_t)N * HEADS);     // N*4
  float* nf = A;            // N*32 node feats (reuse)
  float* w  = el;           // N    sigmoid gates
  float* hsum = er;         // G*32
  unsigned* hmax = emax;    // G*32

  const int n4 = N * HEADS;
  const int e4 = E * HEADS;
  const int gblk = cdiv(N, 64);

  // ===================== Layer 1 =====================
  gemm_tiled<IN_FEATS><<<gblk, 256, 0, stream>>>(feats, fc1_w, A, N);
  gemm_tiled<IN_FEATS><<<gblk, 256, 0, stream>>>(feats, res1_w, B, N);
  scores_kernel<<<cdiv(n4, 256), 256, 0, stream>>>(A, attn_l1, attn_r1, el, er, N);
  init_softmax_kernel<<<cdiv(n4, 256), 256, 0, stream>>>(emax, denom, n4);
  hipMemsetAsync(C, 0, (size_t)N * HF * sizeof(float), stream);
  edge_max_kernel<<<cdiv(e4, 256), 256, 0, stream>>>(src, dst, el, er, emax, ee, E);
  edge_exp_kernel<<<cdiv(e4, 256), 256, 0, stream>>>(dst, emax, ee, denom, E);
  edge_agg_kernel<<<cdiv((long long)E * HF, 256), 256, 0, stream>>>(src, dst, ee, A, C, E);
  finalize1_kernel<<<cdiv((long long)N * HF, 256), 256, 0, stream>>>(B, C, denom, bias1, N);

  // ===================== Layer 2 =====================
  gemm_tiled<HF><<<gblk, 256, 0, stream>>>(B, fc2_w, A, N);
  scores_kernel<<<cdiv(n4, 256), 256, 0, stream>>>(A, attn_l2, attn_r2, el, er, N);
  init_softmax_kernel<<<cdiv(n4, 256), 256, 0, stream>>>(emax, denom, n4);
  hipMemsetAsync(C, 0, (size_t)N * HF * sizeof(float), stream);
  edge_max_kernel<<<cdiv(e4, 256), 256, 0, stream>>>(src, dst, el, er, emax, ee, E);
  edge_exp_kernel<<<cdiv(e4, 256), 256, 0, stream>>>(dst, emax, ee, denom, E);
  edge_agg_kernel<<<cdiv((long long)E * HF, 256), 256, 0, stream>>>(src, dst, ee, A, C, E);
  finalize2_kernel<<<cdiv((long long)N * OUTF, 256), 256, 0, stream>>>(nf, C, denom, B, bias2, N);

  // ===================== Readout =====================
  node_w_kernel<<<cdiv(N, 256), 256, 0, stream>>>(nf, ww, wb, w, N);
  hipMemsetAsync(hsum, 0, (size_t)G * OUTF * sizeof(float), stream);
  init_readout_kernel<<<cdiv(G * OUTF, 256), 256, 0, stream>>>(hmax, G * OUTF);
  readout_kernel<<<cdiv((long long)N * OUTF, 256), 256, 0, stream>>>(nf, w, gids, hsum, hmax, N);
  final_gemm_kernel<<<cdiv(G, 2), 256, 0, stream>>>(hsum, hmax, tw, tb, out, G);
}

// Round 3
// 662.179 us; speedup vs baseline: 4.0729x; 2.0142x over previous
//
#include <hip/hip_runtime.h>

// ---------------------------------------------------------------------------
// DGL GAT (2-layer, heads=4, out=32) + WeightedSumAndMax readout, f32.
// Round 2: on-the-fly dst-sorted CSR; gather-based fused edge-softmax and
//          aggregate+epilogue kernels (one wave per node). No big atomics.
// ---------------------------------------------------------------------------

#define HEADS 4
#define OUTF 32
#define HF 128            // HEADS*OUTF
#define IN_FEATS 74
#define PRED_DIM 128
#define NEG_SLOPE 0.2f
#define NEG_INF_ENC 0x007fffffu   // enc_f(-inf)

__device__ __forceinline__ unsigned enc_f(float f) {
  unsigned u = __float_as_uint(f);
  return (u & 0x80000000u) ? ~u : (u | 0x80000000u);
}
__device__ __forceinline__ float dec_f(unsigned k) {
  return (k & 0x80000000u) ? __uint_as_float(k & 0x7fffffffu)
                           : __uint_as_float(~k);
}

// ========================= node GEMM (round-1) =============================
// out[n][j] = dot(X[n,:K], W[:K,j]). 64 nodes x 128 cols/block, 8x4 per thr.
template <int K>
__global__ __launch_bounds__(256) void gemm_tiled(
    const float* __restrict__ X, const float* __restrict__ W,
    float* __restrict__ out, int N) {
  constexpr int BK = 32;
  constexpr int APAD = 68;
  __shared__ float as[BK * APAD];
  __shared__ float bs[BK * HF];
  const int tid = threadIdx.x;
  const int tx = tid & 31;
  const int ty = tid >> 5;
  const int j4 = tx * 4;
  const int nb = ty * 8;
  const int n0 = blockIdx.x * 64;

  float acc[8][4] = {};
  for (int k0 = 0; k0 < K; k0 += BK) {
#pragma unroll
    for (int i = 0; i < 8; ++i) {
      int idx = i * 256 + tid;
      int kk = idx & 31, nl = idx >> 5;
      int n = n0 + nl, k = k0 + kk;
      float v = 0.f;
      if (n < N && k < K) v = X[(size_t)n * K + k];
      as[kk * APAD + nl] = v;
    }
#pragma unroll
    for (int i = 0; i < 16; ++i) {
      int idx = i * 256 + tid;
      int kk = idx >> 7, c = idx & 127;
      int k = k0 + kk;
      bs[idx] = (k < K) ? W[(size_t)k * HF + c] : 0.f;
    }
    __syncthreads();
#pragma unroll 8
    for (int kk = 0; kk < BK; ++kk) {
      float4 wv = *(const float4*)&bs[kk * HF + j4];
      float4 a0 = *(const float4*)&as[kk * APAD + nb];
      float4 a1 = *(const float4*)&as[kk * APAD + nb + 4];
      float av[8] = {a0.x, a0.y, a0.z, a0.w, a1.x, a1.y, a1.z, a1.w};
#pragma unroll
      for (int i = 0; i < 8; ++i) {
        acc[i][0] = fmaf(av[i], wv.x, acc[i][0]);
        acc[i][1] = fmaf(av[i], wv.y, acc[i][1]);
        acc[i][2] = fmaf(av[i], wv.z, acc[i][2]);
        acc[i][3] = fmaf(av[i], wv.w, acc[i][3]);
      }
    }
    __syncthreads();
  }
#pragma unroll
  for (int i = 0; i < 8; ++i) {
    int n = n0 + nb + i;
    if (n < N)
      *(float4*)&out[(size_t)n * HF + j4] =
          make_float4(acc[i][0], acc[i][1], acc[i][2], acc[i][3]);
  }
}

// ============================ CSR build ====================================
__global__ __launch_bounds__(256) void hist_kernel(
    const int* __restrict__ dst, int* __restrict__ deg, int E) {
  int e = blockIdx.x * 256 + threadIdx.x;
  if (e < E) atomicAdd(&deg[dst[e]], 1);
}

// scan1: 2048 elems/block, exclusive prefix into row_ptr (sans block offset)
__global__ __launch_bounds__(256) void scan1_kernel(
    const int* __restrict__ deg, int* __restrict__ row_ptr,
    int* __restrict__ bsum, int N) {
  const int base = blockIdx.x * 2048;
  const int tbase = base + threadIdx.x * 8;
  int vals[8];
  int tsum = 0;
#pragma unroll
  for (int i = 0; i < 8; ++i) {
    int idx = tbase + i;
    vals[i] = (idx < N) ? deg[idx] : 0;
    tsum += vals[i];
  }
  const int lane = threadIdx.x & 63, wv = threadIdx.x >> 6;
  int incl = tsum;
#pragma unroll
  for (int off = 1; off < 64; off <<= 1) {
    int nv = __shfl_up(incl, off);
    if (lane >= off) incl += nv;
  }
  __shared__ int wsum[4];
  if (lane == 63) wsum[wv] = incl;
  __syncthreads();
  int woff = 0;
  for (int w = 0; w < wv; ++w) woff += wsum[w];
  int run = woff + incl - tsum;
#pragma unroll
  for (int i = 0; i < 8; ++i) {
    int idx = tbase + i;
    if (idx < N) row_ptr[idx] = run;
    run += vals[i];
  }
  if (threadIdx.x == 255) bsum[blockIdx.x] = woff + incl;
}

// scan2: single wave, exclusive scan of NB block sums (any NB)
__global__ __launch_bounds__(64) void scan2_kernel(
    const int* __restrict__ bsum, int* __restrict__ bpre, int NB) {
  const int lane = threadIdx.x;
  int running = 0;
  for (int c = 0; c < NB; c += 64) {
    int v = (c + lane < NB) ? bsum[c + lane] : 0;
    int incl = v;
#pragma unroll
    for (int off = 1; off < 64; off <<= 1) {
      int nv = __shfl_up(incl, off);
      if (lane >= off) incl += nv;
    }
    if (c + lane < NB) bpre[c + lane] = running + incl - v;
    running += __shfl(incl, 63);
  }
}

__global__ __launch_bounds__(256) void scan3_kernel(
    int* __restrict__ row_ptr, const int* __restrict__ bpre, int N, int E) {
  int t = blockIdx.x * 256 + threadIdx.x;
  if (t < N) row_ptr[t] += bpre[t >> 11];
  if (t == 0) row_ptr[N] = E;
}

__global__ __launch_bounds__(256) void scatter_kernel(
    const int* __restrict__ src, const int* __restrict__ dst,
    const int* __restrict__ row_ptr, int* __restrict__ cursor,
    int* __restrict__ ssorted, int E) {
  int e = blockIdx.x * 256 + threadIdx.x;
  if (e >= E) return;
  int d = dst[e];
  int pos = row_ptr[d] + atomicAdd(&cursor[d], 1);
  ssorted[pos] = src[e];
}

// ===================== attention scores & softmax ==========================
// el[n][h] = dot(feat[n][h], attn_l[h]); er likewise. 1 thread / (n,h).
__global__ __launch_bounds__(256) void scores_kernel(
    const float* __restrict__ feat, const float* __restrict__ attn_l,
    const float* __restrict__ attn_r, float* __restrict__ el,
    float* __restrict__ er, int N) {
  int t = blockIdx.x * 256 + threadIdx.x;
  if (t >= N * HEADS) return;
  int h = t & 3;
  const float* f = feat + (size_t)t * OUTF;
  const float* al = attn_l + h * OUTF;
  const float* ar = attn_r + h * OUTF;
  float sl = 0.f, sr = 0.f;
#pragma unroll
  for (int k = 0; k < OUTF; ++k) {
    float v = f[k];
    sl = fmaf(v, al[k], sl);
    sr = fmaf(v, ar[k], sr);
  }
  el[t] = sl;
  er[t] = sr;
}

// One wave per dst node. lane = eslot*4 + h (16 edge slots x 4 heads).
// Writes NORMALIZED attention coefficients to ee (sorted edge order).
__global__ __launch_bounds__(256) void edge_softmax_kernel(
    const int* __restrict__ row_ptr, const int* __restrict__ ssorted,
    const float* __restrict__ el, const float* __restrict__ er,
    float* __restrict__ ee, int N) {
  int n = blockIdx.x * 4 + (threadIdx.x >> 6);
  if (n >= N) return;
  const int lane = threadIdx.x & 63;
  const int eslot = lane >> 2, h = lane & 3;
  const int rb = row_ptr[n], re = row_ptr[n + 1];
  const float ern = er[n * HEADS + h];

  float m = -INFINITY;
  for (int base = rb; base < re; base += 16) {
    int e = base + eslot;
    if (e < re) {
      int s = ssorted[e];
      float v = el[s * HEADS + h] + ern;
      v = (v >= 0.f) ? v : NEG_SLOPE * v;
      m = fmaxf(m, v);
    }
  }
#pragma unroll
  for (int off = 4; off < 64; off <<= 1) m = fmaxf(m, __shfl_xor(m, off));

  float ssum = 0.f;
  for (int base = rb; base < re; base += 16) {
    int e = base + eslot;
    if (e < re) {
      int s = ssorted[e];
      float v = el[s * HEADS + h] + ern;
      v = (v >= 0.f) ? v : NEG_SLOPE * v;
      float x = expf(v - m);
      ee[e * HEADS + h] = x;  // contiguous 256B per wave iteration
      ssum += x;
    }
  }
#pragma unroll
  for (int off = 4; off < 64; off <<= 1) ssum += __shfl_xor(ssum, off);
  float inv = 1.f / ssum;

  for (int base = rb; base < re; base += 16) {
    int e = base + eslot;
    if (e < re) ee[e * HEADS + h] *= inv;
  }
}

// ===================== fused aggregate + epilogue ==========================
// One wave per node; lane holds cols (2*lane, 2*lane+1), head = lane>>4.
// Layer 1: B[n][:] = elu( sum_e a*feat[src] + B[n][:] + bias[:] )  (in place)
__global__ __launch_bounds__(256) void agg1_kernel(
    const int* __restrict__ row_ptr, const int* __restrict__ ssorted,
    const float* __restrict__ ee, const float* __restrict__ feat,
    float* __restrict__ B, const float* __restrict__ bias, int N) {
  int n = blockIdx.x * 4 + (threadIdx.x >> 6);
  if (n >= N) return;
  const int lane = threadIdx.x & 63;
  const int c2 = lane * 2, h = lane >> 4;
  const int rb = row_ptr[n], re = row_ptr[n + 1];

  float ax = 0.f, ay = 0.f;
  int e = rb;
  for (; e + 1 < re; e += 2) {
    int s0 = ssorted[e], s1 = ssorted[e + 1];
    float a0 = ee[e * HEADS + h], a1 = ee[(e + 1) * HEADS + h];
    float2 f0 = *(const float2*)&feat[(size_t)s0 * HF + c2];
    float2 f1 = *(const float2*)&feat[(size_t)s1 * HF + c2];
    ax = fmaf(a0, f0.x, ax); ay = fmaf(a0, f0.y, ay);
    ax = fmaf(a1, f1.x, ax); ay = fmaf(a1, f1.y, ay);
  }
  if (e < re) {
    int s = ssorted[e];
    float a = ee[e * HEADS + h];
    float2 f = *(const float2*)&feat[(size_t)s * HF + c2];
    ax = fmaf(a, f.x, ax); ay = fmaf(a, f.y, ay);
  }
  float2 r = *(const float2*)&B[(size_t)n * HF + c2];
  float2 bi = *(const float2*)&bias[c2];
  float vx = ax + r.x + bi.x;
  float vy = ay + r.y + bi.y;
  vx = (vx > 0.f) ? vx : expm1f(vx);
  vy = (vy > 0.f) ? vy : expm1f(vy);
  *(float2*)&B[(size_t)n * HF + c2] = make_float2(vx, vy);
}

// Layer 2: nf[n][f] = mean_h( agg + h1[n][h*32+f] + bias[h*32+f] )
__global__ __launch_bounds__(256) void agg2_kernel(
    const int* __restrict__ row_ptr, const int* __restrict__ ssorted,
    const float* __restrict__ ee, const float* __restrict__ feat,
    const float* __restrict__ h1, const float* __restrict__ bias,
    float* __restrict__ nf, int N) {
  int n = blockIdx.x * 4 + (threadIdx.x >> 6);
  if (n >= N) return;
  const int lane = threadIdx.x & 63;
  const int c2 = lane * 2, h = lane >> 4;
  const int rb = row_ptr[n], re = row_ptr[n + 1];

  float ax = 0.f, ay = 0.f;
  int e = rb;
  for (; e + 1 < re; e += 2) {
    int s0 = ssorted[e], s1 = ssorted[e + 1];
    float a0 = ee[e * HEADS + h], a1 = ee[(e + 1) * HEADS + h];
    float2 f0 = *(const float2*)&feat[(size_t)s0 * HF + c2];
    float2 f1 = *(const float2*)&feat[(size_t)s1 * HF + c2];
    ax = fmaf(a0, f0.x, ax); ay = fmaf(a0, f0.y, ay);
    ax = fmaf(a1, f1.x, ax); ay = fmaf(a1, f1.y, ay);
  }
  if (e < re) {
    int s = ssorted[e];
    float a = ee[e * HEADS + h];
    float2 f = *(const float2*)&feat[(size_t)s * HF + c2];
    ax = fmaf(a, f.x, ax); ay = fmaf(a, f.y, ay);
  }
  float2 r = *(const float2*)&h1[(size_t)n * HF + c2];
  float2 bi = *(const float2*)&bias[c2];
  ax += r.x + bi.x;
  ay += r.y + bi.y;
  // sum over 4 heads: lanes l, l^16, l^32, l^48 hold same f pair
#pragma unroll
  for (int off = 16; off < 64; off <<= 1) {
    ax += __shfl_xor(ax, off);
    ay += __shfl_xor(ay, off);
  }
  if (lane < 16)
    *(float2*)&nf[(size_t)n * OUTF + (c2 & 31)] =
        make_float2(0.25f * ax, 0.25f * ay);
}

// ============================ readout ======================================
__global__ __launch_bounds__(256) void node_w_kernel(
    const float* __restrict__ nf, const float* __restrict__ ww,
    const float* __restrict__ wb, float* __restrict__ w, int N) {
  int n = blockIdx.x * 256 + threadIdx.x;
  if (n >= N) return;
  float s = wb[0];
  const float* x = nf + (size_t)n * OUTF;
#pragma unroll
  for (int k = 0; k < OUTF; ++k) s = fmaf(x[k], ww[k], s);
  w[n] = 1.f / (1.f + expf(-s));
}

__global__ __launch_bounds__(256) void init_readout_kernel(
    unsigned* __restrict__ hmax, int g32) {
  int t = blockIdx.x * 256 + threadIdx.x;
  if (t >= g32) return;
  hmax[t] = NEG_INF_ENC;
}

__global__ __launch_bounds__(256) void readout_kernel(
    const float* __restrict__ nf, const float* __restrict__ w,
    const int* __restrict__ gids, float* __restrict__ hsum,
    unsigned* __restrict__ hmax, int N) {
  int t = blockIdx.x * 256 + threadIdx.x;
  if (t >= N * OUTF) return;
  int n = t >> 5, f = t & 31;
  int g = gids[n];
  float v = nf[t];
  atomicAdd(&hsum[g * OUTF + f], w[n] * v);
  atomicMax(&hmax[g * OUTF + f], enc_f(v));
}

__global__ __launch_bounds__(256) void final_gemm_kernel(
    const float* __restrict__ hsum, const unsigned* __restrict__ hmax,
    const float* __restrict__ tw, const float* __restrict__ tb,
    float* __restrict__ out, int G) {
  __shared__ float tws[64 * PRED_DIM];
  for (int i = threadIdx.x; i < 64 * PRED_DIM; i += 256) tws[i] = tw[i];
  __syncthreads();
  int g = blockIdx.x * 2 + (threadIdx.x >> 7);
  int p = threadIdx.x & 127;
  if (g >= G) return;
  float acc = tb[p];
#pragma unroll
  for (int k = 0; k < OUTF; ++k)
    acc = fmaf(hsum[g * OUTF + k], tws[k * PRED_DIM + p], acc);
#pragma unroll
  for (int k = 0; k < OUTF; ++k)
    acc = fmaf(dec_f(hmax[g * OUTF + k]), tws[(OUTF + k) * PRED_DIM + p], acc);
  out[(size_t)g * PRED_DIM + p] = acc;
}

static inline int cdiv(long long a, int b) { return (int)((a + b - 1) / b); }

extern "C" void kernel_launch(void* const* d_in, const int* in_sizes, int n_in,
                              void* d_out, int out_size, void* d_ws,
                              size_t ws_size, hipStream_t stream) {
  const float* feats   = (const float*)d_in[0];
  const int*   src     = (const int*)d_in[1];
  const int*   dst     = (const int*)d_in[2];
  const int*   gids    = (const int*)d_in[3];
  const float* fc1_w   = (const float*)d_in[4];
  const float* attn_l1 = (const float*)d_in[5];
  const float* attn_r1 = (const float*)d_in[6];
  const float* res1_w  = (const float*)d_in[7];
  const float* bias1   = (const float*)d_in[8];
  const float* fc2_w   = (const float*)d_in[9];
  const float* attn_l2 = (const float*)d_in[10];
  const float* attn_r2 = (const float*)d_in[11];
  const float* bias2   = (const float*)d_in[12];
  const float* ww      = (const float*)d_in[13];
  const float* wb      = (const float*)d_in[14];
  const float* tw      = (const float*)d_in[15];
  const float* tb      = (const float*)d_in[16];
  float* out = (float*)d_out;

  const int N = in_sizes[0] / IN_FEATS;  // 100000
  const int E = in_sizes[1];             // 900000
  const int G = out_size / PRED_DIM;     // 2048
  const int NB = cdiv(N, 2048);          // scan blocks

  // ---- workspace layout ----
  float* A  = (float*)d_ws;              // N*128  feat1 / feat2
  float* B  = A + (size_t)N * HF;        // N*128  res1 -> h1 (in place)
  float* nf = B + (size_t)N * HF;        // N*32   final node feats
  float* ee = nf + (size_t)N * OUTF;     // E*4    normalized attn coefs
  float* el = ee + (size_t)E * HEADS;    // N*4
  float* er = el + (size_t)N * HEADS;    // N*4
  int* deg     = (int*)(er + (size_t)N * HEADS);  // N
  int* cursor  = deg + N;                         // N
  int* row_ptr = cursor + N;                      // N+1
  int* ssorted = row_ptr + (N + 1);               // E
  int* bsum    = ssorted + E;                     // NB
  int* bpre    = bsum + NB;                       // NB
  float* w = (float*)deg;    // N  (deg free after scatter)
  float* hsum = el;          // G*32 (el free after layer 2)
  unsigned* hmax = (unsigned*)er;  // G*32

  const int n4 = N * HEADS;
  const int gblk = cdiv(N, 64);
  const int nwblk = cdiv(N, 4);  // wave-per-node kernels

  // ===================== CSR build (once per call) ====================
  hipMemsetAsync(deg, 0, (size_t)N * sizeof(int), stream);
  hipMemsetAsync(cursor, 0, (size_t)N * sizeof(int), stream);
  hist_kernel<<<cdiv(E, 256), 256, 0, stream>>>(dst, deg, E);
  scan1_kernel<<<NB, 256, 0, stream>>>(deg, row_ptr, bsum, N);
  scan2_kernel<<<1, 64, 0, stream>>>(bsum, bpre, NB);
  scan3_kernel<<<cdiv(N, 256), 256, 0, stream>>>(row_ptr, bpre, N, E);
  scatter_kernel<<<cdiv(E, 256), 256, 0, stream>>>(src, dst, row_ptr, cursor,
                                                   ssorted, E);

  // ===================== Layer 1 =====================
  gemm_tiled<IN_FEATS><<<gblk, 256, 0, stream>>>(feats, fc1_w, A, N);
  gemm_tiled<IN_FEATS><<<gblk, 256, 0, stream>>>(feats, res1_w, B, N);
  scores_kernel<<<cdiv(n4, 256), 256, 0, stream>>>(A, attn_l1, attn_r1, el, er, N);
  edge_softmax_kernel<<<nwblk, 256, 0, stream>>>(row_ptr, ssorted, el, er, ee, N);
  agg1_kernel<<<nwblk, 256, 0, stream>>>(row_ptr, ssorted, ee, A, B, bias1, N);

  // ===================== Layer 2 =====================
  gemm_tiled<HF><<<gblk, 256, 0, stream>>>(B, fc2_w, A, N);
  scores_kernel<<<cdiv(n4, 256), 256, 0, stream>>>(A, attn_l2, attn_r2, el, er, N);
  edge_softmax_kernel<<<nwblk, 256, 0, stream>>>(row_ptr, ssorted, el, er, ee, N);
  agg2_kernel<<<nwblk, 256, 0, stream>>>(row_ptr, ssorted, ee, A, B, bias2, nf, N);

  // ===================== Readout =====================
  node_w_kernel<<<cdiv(N, 256), 256, 0, stream>>>(nf, ww, wb, w, N);
  hipMemsetAsync(hsum, 0, (size_t)G * OUTF * sizeof(float), stream);
  init_readout_kernel<<<cdiv(G * OUTF, 256), 256, 0, stream>>>(hmax, G * OUTF);
  readout_kernel<<<cdiv((long long)N * OUTF, 256), 256, 0, stream>>>(
      nf, w, gids, hsum, hmax, N);
  final_gemm_kernel<<<cdiv(G, 2), 256, 0, stream>>>(hsum, hmax, tw, tb, out, G);
}

// Round 4
// 618.253 us; speedup vs baseline: 4.3622x; 1.0710x over previous
//
#include <hip/hip_runtime.h>
#include <hip/hip_bf16.h>

// ---------------------------------------------------------------------------
// DGL GAT (2-layer, heads=4, out=32) + WeightedSumAndMax readout.
// Round 3: gathered feature matrix A stored in bf16 (halves edge-gather
//          traffic); softmax stores unnormalized exp + per-(n,h) reciprocal.
// ---------------------------------------------------------------------------

#define HEADS 4
#define OUTF 32
#define HF 128            // HEADS*OUTF
#define IN_FEATS 74
#define PRED_DIM 128
#define NEG_SLOPE 0.2f
#define NEG_INF_ENC 0x007fffffu   // enc_f(-inf)

typedef __hip_bfloat16 bf16;
typedef __hip_bfloat162 bf16x2;

__device__ __forceinline__ unsigned enc_f(float f) {
  unsigned u = __float_as_uint(f);
  return (u & 0x80000000u) ? ~u : (u | 0x80000000u);
}
__device__ __forceinline__ float dec_f(unsigned k) {
  return (k & 0x80000000u) ? __uint_as_float(k & 0x7fffffffu)
                           : __uint_as_float(~k);
}
__device__ __forceinline__ unsigned pack_bf16(float a, float b) {
  bf16x2 h = __float22bfloat162_rn(make_float2(a, b));
  return *(unsigned*)&h;
}
__device__ __forceinline__ float2 unpack_bf16(unsigned u) {
  bf16x2 h = *(bf16x2*)&u;
  return __bfloat1622float2(h);
}

// ========================= node GEMM =============================
// out[n][j] = dot(X[n,:K], W[:K,j]). 64 nodes x 128 cols/block, 8x4 per thr.
// OUT_BF16: write bf16 (packed), else f32.
template <int K, bool OUT_BF16>
__global__ __launch_bounds__(256) void gemm_tiled(
    const float* __restrict__ X, const float* __restrict__ W,
    void* __restrict__ out_v, int N) {
  constexpr int BK = 32;
  constexpr int APAD = 68;
  __shared__ float as[BK * APAD];
  __shared__ float bs[BK * HF];
  const int tid = threadIdx.x;
  const int tx = tid & 31;
  const int ty = tid >> 5;
  const int j4 = tx * 4;
  const int nb = ty * 8;
  const int n0 = blockIdx.x * 64;

  float acc[8][4] = {};
  for (int k0 = 0; k0 < K; k0 += BK) {
#pragma unroll
    for (int i = 0; i < 8; ++i) {
      int idx = i * 256 + tid;
      int kk = idx & 31, nl = idx >> 5;
      int n = n0 + nl, k = k0 + kk;
      float v = 0.f;
      if (n < N && k < K) v = X[(size_t)n * K + k];
      as[kk * APAD + nl] = v;
    }
#pragma unroll
    for (int i = 0; i < 16; ++i) {
      int idx = i * 256 + tid;
      int kk = idx >> 7, c = idx & 127;
      int k = k0 + kk;
      bs[idx] = (k < K) ? W[(size_t)k * HF + c] : 0.f;
    }
    __syncthreads();
#pragma unroll 8
    for (int kk = 0; kk < BK; ++kk) {
      float4 wv = *(const float4*)&bs[kk * HF + j4];
      float4 a0 = *(const float4*)&as[kk * APAD + nb];
      float4 a1 = *(const float4*)&as[kk * APAD + nb + 4];
      float av[8] = {a0.x, a0.y, a0.z, a0.w, a1.x, a1.y, a1.z, a1.w};
#pragma unroll
      for (int i = 0; i < 8; ++i) {
        acc[i][0] = fmaf(av[i], wv.x, acc[i][0]);
        acc[i][1] = fmaf(av[i], wv.y, acc[i][1]);
        acc[i][2] = fmaf(av[i], wv.z, acc[i][2]);
        acc[i][3] = fmaf(av[i], wv.w, acc[i][3]);
      }
    }
    __syncthreads();
  }
#pragma unroll
  for (int i = 0; i < 8; ++i) {
    int n = n0 + nb + i;
    if (n >= N) continue;
    if (OUT_BF16) {
      bf16* out = (bf16*)out_v;
      *(uint2*)&out[(size_t)n * HF + j4] =
          make_uint2(pack_bf16(acc[i][0], acc[i][1]),
                     pack_bf16(acc[i][2], acc[i][3]));
    } else {
      float* out = (float*)out_v;
      *(float4*)&out[(size_t)n * HF + j4] =
          make_float4(acc[i][0], acc[i][1], acc[i][2], acc[i][3]);
    }
  }
}

// ============================ CSR build ====================================
__global__ __launch_bounds__(256) void hist_kernel(
    const int* __restrict__ dst, int* __restrict__ deg, int E) {
  int e = blockIdx.x * 256 + threadIdx.x;
  if (e < E) atomicAdd(&deg[dst[e]], 1);
}

__global__ __launch_bounds__(256) void scan1_kernel(
    const int* __restrict__ deg, int* __restrict__ row_ptr,
    int* __restrict__ bsum, int N) {
  const int base = blockIdx.x * 2048;
  const int tbase = base + threadIdx.x * 8;
  int vals[8];
  int tsum = 0;
#pragma unroll
  for (int i = 0; i < 8; ++i) {
    int idx = tbase + i;
    vals[i] = (idx < N) ? deg[idx] : 0;
    tsum += vals[i];
  }
  const int lane = threadIdx.x & 63, wv = threadIdx.x >> 6;
  int incl = tsum;
#pragma unroll
  for (int off = 1; off < 64; off <<= 1) {
    int nv = __shfl_up(incl, off);
    if (lane >= off) incl += nv;
  }
  __shared__ int wsum[4];
  if (lane == 63) wsum[wv] = incl;
  __syncthreads();
  int woff = 0;
  for (int w = 0; w < wv; ++w) woff += wsum[w];
  int run = woff + incl - tsum;
#pragma unroll
  for (int i = 0; i < 8; ++i) {
    int idx = tbase + i;
    if (idx < N) row_ptr[idx] = run;
    run += vals[i];
  }
  if (threadIdx.x == 255) bsum[blockIdx.x] = woff + incl;
}

__global__ __launch_bounds__(64) void scan2_kernel(
    const int* __restrict__ bsum, int* __restrict__ bpre, int NB) {
  const int lane = threadIdx.x;
  int running = 0;
  for (int c = 0; c < NB; c += 64) {
    int v = (c + lane < NB) ? bsum[c + lane] : 0;
    int incl = v;
#pragma unroll
    for (int off = 1; off < 64; off <<= 1) {
      int nv = __shfl_up(incl, off);
      if (lane >= off) incl += nv;
    }
    if (c + lane < NB) bpre[c + lane] = running + incl - v;
    running += __shfl(incl, 63);
  }
}

__global__ __launch_bounds__(256) void scan3_kernel(
    int* __restrict__ row_ptr, const int* __restrict__ bpre, int N, int E) {
  int t = blockIdx.x * 256 + threadIdx.x;
  if (t < N) row_ptr[t] += bpre[t >> 11];
  if (t == 0) row_ptr[N] = E;
}

__global__ __launch_bounds__(256) void scatter_kernel(
    const int* __restrict__ src, const int* __restrict__ dst,
    const int* __restrict__ row_ptr, int* __restrict__ cursor,
    int* __restrict__ ssorted, int E) {
  int e = blockIdx.x * 256 + threadIdx.x;
  if (e >= E) return;
  int d = dst[e];
  int pos = row_ptr[d] + atomicAdd(&cursor[d], 1);
  ssorted[pos] = src[e];
}

// ===================== attention scores & softmax ==========================
// el[n][h] = dot(feat[n][h], attn_l[h]); er likewise. 1 thread / (n,h).
__global__ __launch_bounds__(256) void scores_kernel(
    const bf16* __restrict__ feat, const float* __restrict__ attn_l,
    const float* __restrict__ attn_r, float* __restrict__ el,
    float* __restrict__ er, int N) {
  int t = blockIdx.x * 256 + threadIdx.x;
  if (t >= N * HEADS) return;
  int h = t & 3;
  const bf16x2* f2 = (const bf16x2*)(feat + (size_t)t * OUTF);
  const float* al = attn_l + h * OUTF;
  const float* ar = attn_r + h * OUTF;
  float sl = 0.f, sr = 0.f;
#pragma unroll
  for (int k = 0; k < OUTF / 2; ++k) {
    float2 v = __bfloat1622float2(f2[k]);
    sl = fmaf(v.x, al[2 * k], sl);
    sl = fmaf(v.y, al[2 * k + 1], sl);
    sr = fmaf(v.x, ar[2 * k], sr);
    sr = fmaf(v.y, ar[2 * k + 1], sr);
  }
  el[t] = sl;
  er[t] = sr;
}

// One wave per dst node. lane = eslot*4 + h (16 edge slots x 4 heads).
// Writes UNNORMALIZED exp to ee, 1/denominator to invd[n*4+h].
__global__ __launch_bounds__(256) void edge_softmax_kernel(
    const int* __restrict__ row_ptr, const int* __restrict__ ssorted,
    const float* __restrict__ el, const float* __restrict__ er,
    float* __restrict__ ee, float* __restrict__ invd, int N) {
  int n = blockIdx.x * 4 + (threadIdx.x >> 6);
  if (n >= N) return;
  const int lane = threadIdx.x & 63;
  const int eslot = lane >> 2, h = lane & 3;
  const int rb = row_ptr[n], re = row_ptr[n + 1];
  const float ern = er[n * HEADS + h];

  float m = -INFINITY;
  for (int base = rb; base < re; base += 16) {
    int e = base + eslot;
    if (e < re) {
      int s = ssorted[e];
      float v = el[s * HEADS + h] + ern;
      v = (v >= 0.f) ? v : NEG_SLOPE * v;
      m = fmaxf(m, v);
    }
  }
#pragma unroll
  for (int off = 4; off < 64; off <<= 1) m = fmaxf(m, __shfl_xor(m, off));

  float ssum = 0.f;
  for (int base = rb; base < re; base += 16) {
    int e = base + eslot;
    if (e < re) {
      int s = ssorted[e];
      float v = el[s * HEADS + h] + ern;
      v = (v >= 0.f) ? v : NEG_SLOPE * v;
      float x = expf(v - m);
      ee[e * HEADS + h] = x;
      ssum += x;
    }
  }
#pragma unroll
  for (int off = 4; off < 64; off <<= 1) ssum += __shfl_xor(ssum, off);
  if (lane < 4) invd[n * HEADS + h] = 1.f / ssum;
}

// ===================== fused aggregate + epilogue ==========================
// One wave per node; lane holds cols (2*lane, 2*lane+1), head = lane>>4.
// Layer 1: B[n][:] = elu( inv * sum_e x_e*feat[src] + B[n][:] + bias[:] )
__global__ __launch_bounds__(256) void agg1_kernel(
    const int* __restrict__ row_ptr, const int* __restrict__ ssorted,
    const float* __restrict__ ee, const float* __restrict__ invd,
    const bf16* __restrict__ feat, float* __restrict__ B,
    const float* __restrict__ bias, int N) {
  int n = blockIdx.x * 4 + (threadIdx.x >> 6);
  if (n >= N) return;
  const int lane = threadIdx.x & 63;
  const int c2 = lane * 2, h = lane >> 4;
  const int rb = row_ptr[n], re = row_ptr[n + 1];

  float ax = 0.f, ay = 0.f;
  int e = rb;
  for (; e + 1 < re; e += 2) {
    int s0 = ssorted[e], s1 = ssorted[e + 1];
    float a0 = ee[e * HEADS + h], a1 = ee[(e + 1) * HEADS + h];
    float2 f0 = unpack_bf16(*(const unsigned*)&feat[(size_t)s0 * HF + c2]);
    float2 f1 = unpack_bf16(*(const unsigned*)&feat[(size_t)s1 * HF + c2]);
    ax = fmaf(a0, f0.x, ax); ay = fmaf(a0, f0.y, ay);
    ax = fmaf(a1, f1.x, ax); ay = fmaf(a1, f1.y, ay);
  }
  if (e < re) {
    int s = ssorted[e];
    float a = ee[e * HEADS + h];
    float2 f = unpack_bf16(*(const unsigned*)&feat[(size_t)s * HF + c2]);
    ax = fmaf(a, f.x, ax); ay = fmaf(a, f.y, ay);
  }
  float inv = invd[n * HEADS + h];
  float2 r = *(const float2*)&B[(size_t)n * HF + c2];
  float2 bi = *(const float2*)&bias[c2];
  float vx = ax * inv + r.x + bi.x;
  float vy = ay * inv + r.y + bi.y;
  vx = (vx > 0.f) ? vx : expm1f(vx);
  vy = (vy > 0.f) ? vy : expm1f(vy);
  *(float2*)&B[(size_t)n * HF + c2] = make_float2(vx, vy);
}

// Layer 2: nf[n][f] = mean_h( inv*agg + h1[n][h*32+f] + bias[h*32+f] )
__global__ __launch_bounds__(256) void agg2_kernel(
    const int* __restrict__ row_ptr, const int* __restrict__ ssorted,
    const float* __restrict__ ee, const float* __restrict__ invd,
    const bf16* __restrict__ feat, const float* __restrict__ h1,
    const float* __restrict__ bias, float* __restrict__ nf, int N) {
  int n = blockIdx.x * 4 + (threadIdx.x >> 6);
  if (n >= N) return;
  const int lane = threadIdx.x & 63;
  const int c2 = lane * 2, h = lane >> 4;
  const int rb = row_ptr[n], re = row_ptr[n + 1];

  float ax = 0.f, ay = 0.f;
  int e = rb;
  for (; e + 1 < re; e += 2) {
    int s0 = ssorted[e], s1 = ssorted[e + 1];
    float a0 = ee[e * HEADS + h], a1 = ee[(e + 1) * HEADS + h];
    float2 f0 = unpack_bf16(*(const unsigned*)&feat[(size_t)s0 * HF + c2]);
    float2 f1 = unpack_bf16(*(const unsigned*)&feat[(size_t)s1 * HF + c2]);
    ax = fmaf(a0, f0.x, ax); ay = fmaf(a0, f0.y, ay);
    ax = fmaf(a1, f1.x, ax); ay = fmaf(a1, f1.y, ay);
  }
  if (e < re) {
    int s = ssorted[e];
    float a = ee[e * HEADS + h];
    float2 f = unpack_bf16(*(const unsigned*)&feat[(size_t)s * HF + c2]);
    ax = fmaf(a, f.x, ax); ay = fmaf(a, f.y, ay);
  }
  float inv = invd[n * HEADS + h];
  float2 r = *(const float2*)&h1[(size_t)n * HF + c2];
  float2 bi = *(const float2*)&bias[c2];
  ax = ax * inv + r.x + bi.x;
  ay = ay * inv + r.y + bi.y;
#pragma unroll
  for (int off = 16; off < 64; off <<= 1) {
    ax += __shfl_xor(ax, off);
    ay += __shfl_xor(ay, off);
  }
  if (lane < 16)
    *(float2*)&nf[(size_t)n * OUTF + (c2 & 31)] =
        make_float2(0.25f * ax, 0.25f * ay);
}

// ============================ readout ======================================
__global__ __launch_bounds__(256) void node_w_kernel(
    const float* __restrict__ nf, const float* __restrict__ ww,
    const float* __restrict__ wb, float* __restrict__ w, int N) {
  int n = blockIdx.x * 256 + threadIdx.x;
  if (n >= N) return;
  float s = wb[0];
  const float* x = nf + (size_t)n * OUTF;
#pragma unroll
  for (int k = 0; k < OUTF; ++k) s = fmaf(x[k], ww[k], s);
  w[n] = 1.f / (1.f + expf(-s));
}

__global__ __launch_bounds__(256) void init_readout_kernel(
    unsigned* __restrict__ hmax, int g32) {
  int t = blockIdx.x * 256 + threadIdx.x;
  if (t >= g32) return;
  hmax[t] = NEG_INF_ENC;
}

__global__ __launch_bounds__(256) void readout_kernel(
    const float* __restrict__ nf, const float* __restrict__ w,
    const int* __restrict__ gids, float* __restrict__ hsum,
    unsigned* __restrict__ hmax, int N) {
  int t = blockIdx.x * 256 + threadIdx.x;
  if (t >= N * OUTF) return;
  int n = t >> 5, f = t & 31;
  int g = gids[n];
  float v = nf[t];
  atomicAdd(&hsum[g * OUTF + f], w[n] * v);
  atomicMax(&hmax[g * OUTF + f], enc_f(v));
}

__global__ __launch_bounds__(256) void final_gemm_kernel(
    const float* __restrict__ hsum, const unsigned* __restrict__ hmax,
    const float* __restrict__ tw, const float* __restrict__ tb,
    float* __restrict__ out, int G) {
  __shared__ float tws[64 * PRED_DIM];
  for (int i = threadIdx.x; i < 64 * PRED_DIM; i += 256) tws[i] = tw[i];
  __syncthreads();
  int g = blockIdx.x * 2 + (threadIdx.x >> 7);
  int p = threadIdx.x & 127;
  if (g >= G) return;
  float acc = tb[p];
#pragma unroll
  for (int k = 0; k < OUTF; ++k)
    acc = fmaf(hsum[g * OUTF + k], tws[k * PRED_DIM + p], acc);
#pragma unroll
  for (int k = 0; k < OUTF; ++k)
    acc = fmaf(dec_f(hmax[g * OUTF + k]), tws[(OUTF + k) * PRED_DIM + p], acc);
  out[(size_t)g * PRED_DIM + p] = acc;
}

static inline int cdiv(long long a, int b) { return (int)((a + b - 1) / b); }

extern "C" void kernel_launch(void* const* d_in, const int* in_sizes, int n_in,
                              void* d_out, int out_size, void* d_ws,
                              size_t ws_size, hipStream_t stream) {
  const float* feats   = (const float*)d_in[0];
  const int*   src     = (const int*)d_in[1];
  const int*   dst     = (const int*)d_in[2];
  const int*   gids    = (const int*)d_in[3];
  const float* fc1_w   = (const float*)d_in[4];
  const float* attn_l1 = (const float*)d_in[5];
  const float* attn_r1 = (const float*)d_in[6];
  const float* res1_w  = (const float*)d_in[7];
  const float* bias1   = (const float*)d_in[8];
  const float* fc2_w   = (const float*)d_in[9];
  const float* attn_l2 = (const float*)d_in[10];
  const float* attn_r2 = (const float*)d_in[11];
  const float* bias2   = (const float*)d_in[12];
  const float* ww      = (const float*)d_in[13];
  const float* wb      = (const float*)d_in[14];
  const float* tw      = (const float*)d_in[15];
  const float* tb      = (const float*)d_in[16];
  float* out = (float*)d_out;

  const int N = in_sizes[0] / IN_FEATS;  // 100000
  const int E = in_sizes[1];             // 900000
  const int G = out_size / PRED_DIM;     // 2048
  const int NB = cdiv(N, 2048);

  // ---- workspace layout ----
  bf16* A = (bf16*)d_ws;                              // N*128 bf16 (feat1/feat2)
  float* B  = (float*)((char*)d_ws + (size_t)N * HF * 2);  // N*128 f32
  float* nf = B + (size_t)N * HF;        // N*32
  float* ee = nf + (size_t)N * OUTF;     // E*4   unnormalized exp
  float* el = ee + (size_t)E * HEADS;    // N*4
  float* er = el + (size_t)N * HEADS;    // N*4
  float* invd = er + (size_t)N * HEADS;  // N*4
  int* deg     = (int*)(invd + (size_t)N * HEADS);  // N
  int* cursor  = deg + N;                           // N
  int* row_ptr = cursor + N;                        // N+1
  int* ssorted = row_ptr + (N + 1);                 // E
  int* bsum    = ssorted + E;                       // NB
  int* bpre    = bsum + NB;                         // NB
  float* w = (float*)deg;          // N (deg free after scatter)
  float* hsum = el;                // G*32 (el free after softmax2)
  unsigned* hmax = (unsigned*)er;  // G*32

  const int n4 = N * HEADS;
  const int gblk = cdiv(N, 64);
  const int nwblk = cdiv(N, 4);

  // ===================== CSR build =====================
  hipMemsetAsync(deg, 0, (size_t)N * sizeof(int), stream);
  hipMemsetAsync(cursor, 0, (size_t)N * sizeof(int), stream);
  hist_kernel<<<cdiv(E, 256), 256, 0, stream>>>(dst, deg, E);
  scan1_kernel<<<NB, 256, 0, stream>>>(deg, row_ptr, bsum, N);
  scan2_kernel<<<1, 64, 0, stream>>>(bsum, bpre, NB);
  scan3_kernel<<<cdiv(N, 256), 256, 0, stream>>>(row_ptr, bpre, N, E);
  scatter_kernel<<<cdiv(E, 256), 256, 0, stream>>>(src, dst, row_ptr, cursor,
                                                   ssorted, E);

  // ===================== Layer 1 =====================
  gemm_tiled<IN_FEATS, true><<<gblk, 256, 0, stream>>>(feats, fc1_w, A, N);
  gemm_tiled<IN_FEATS, false><<<gblk, 256, 0, stream>>>(feats, res1_w, B, N);
  scores_kernel<<<cdiv(n4, 256), 256, 0, stream>>>(A, attn_l1, attn_r1, el, er, N);
  edge_softmax_kernel<<<nwblk, 256, 0, stream>>>(row_ptr, ssorted, el, er, ee,
                                                 invd, N);
  agg1_kernel<<<nwblk, 256, 0, stream>>>(row_ptr, ssorted, ee, invd, A, B,
                                         bias1, N);

  // ===================== Layer 2 =====================
  gemm_tiled<HF, true><<<gblk, 256, 0, stream>>>(B, fc2_w, A, N);
  scores_kernel<<<cdiv(n4, 256), 256, 0, stream>>>(A, attn_l2, attn_r2, el, er, N);
  edge_softmax_kernel<<<nwblk, 256, 0, stream>>>(row_ptr, ssorted, el, er, ee,
                                                 invd, N);
  agg2_kernel<<<nwblk, 256, 0, stream>>>(row_ptr, ssorted, ee, invd, A, B,
                                         bias2, nf, N);

  // ===================== Readout =====================
  node_w_kernel<<<cdiv(N, 256), 256, 0, stream>>>(nf, ww, wb, w, N);
  hipMemsetAsync(hsum, 0, (size_t)G * OUTF * sizeof(float), stream);
  init_readout_kernel<<<cdiv(G * OUTF, 256), 256, 0, stream>>>(hmax, G * OUTF);
  readout_kernel<<<cdiv((long long)N * OUTF, 256), 256, 0, stream>>>(
      nf, w, gids, hsum, hmax, N);
  final_gemm_kernel<<<cdiv(G, 2), 256, 0, stream>>>(hsum, hmax, tw, tb, out, G);
}

// Round 5
// 516.353 us; speedup vs baseline: 5.2231x; 1.1973x over previous
//
#include <hip/hip_runtime.h>
#include <hip/hip_bf16.h>

// ---------------------------------------------------------------------------
// DGL GAT (2-layer, heads=4, out=32) + WeightedSumAndMax readout.
// Round 4: single-pass fused softmax+aggregate per node (max-subtraction
//          dropped — mathematically neutral for normalized alpha); layer-2
//          epilogue folds head-mean + sigmoid gate + readout atomics.
// ---------------------------------------------------------------------------

#define HEADS 4
#define OUTF 32
#define HF 128            // HEADS*OUTF
#define IN_FEATS 74
#define PRED_DIM 128
#define NEG_SLOPE 0.2f
#define NEG_INF_ENC 0x007fffffu   // enc_f(-inf)

typedef __hip_bfloat16 bf16;
typedef __hip_bfloat162 bf16x2;

__device__ __forceinline__ unsigned enc_f(float f) {
  unsigned u = __float_as_uint(f);
  return (u & 0x80000000u) ? ~u : (u | 0x80000000u);
}
__device__ __forceinline__ float dec_f(unsigned k) {
  return (k & 0x80000000u) ? __uint_as_float(k & 0x7fffffffu)
                           : __uint_as_float(~k);
}
__device__ __forceinline__ unsigned pack_bf16(float a, float b) {
  bf16x2 h = __float22bfloat162_rn(make_float2(a, b));
  return *(unsigned*)&h;
}
__device__ __forceinline__ float2 unpack_bf16(unsigned u) {
  bf16x2 h = *(bf16x2*)&u;
  return __bfloat1622float2(h);
}
__device__ __forceinline__ float lrelu(float v) {
  return (v >= 0.f) ? v : NEG_SLOPE * v;
}

// ========================= node GEMM =============================
// out[n][j] = dot(X[n,:K], W[:K,j]). 64 nodes x 128 cols/block, 8x4 per thr.
template <int K, bool OUT_BF16>
__global__ __launch_bounds__(256) void gemm_tiled(
    const float* __restrict__ X, const float* __restrict__ W,
    void* __restrict__ out_v, int N) {
  constexpr int BK = 32;
  constexpr int APAD = 68;
  __shared__ float as[BK * APAD];
  __shared__ float bs[BK * HF];
  const int tid = threadIdx.x;
  const int tx = tid & 31;
  const int ty = tid >> 5;
  const int j4 = tx * 4;
  const int nb = ty * 8;
  const int n0 = blockIdx.x * 64;

  float acc[8][4] = {};
  for (int k0 = 0; k0 < K; k0 += BK) {
#pragma unroll
    for (int i = 0; i < 8; ++i) {
      int idx = i * 256 + tid;
      int kk = idx & 31, nl = idx >> 5;
      int n = n0 + nl, k = k0 + kk;
      float v = 0.f;
      if (n < N && k < K) v = X[(size_t)n * K + k];
      as[kk * APAD + nl] = v;
    }
#pragma unroll
    for (int i = 0; i < 16; ++i) {
      int idx = i * 256 + tid;
      int kk = idx >> 7, c = idx & 127;
      int k = k0 + kk;
      bs[idx] = (k < K) ? W[(size_t)k * HF + c] : 0.f;
    }
    __syncthreads();
#pragma unroll 8
    for (int kk = 0; kk < BK; ++kk) {
      float4 wv = *(const float4*)&bs[kk * HF + j4];
      float4 a0 = *(const float4*)&as[kk * APAD + nb];
      float4 a1 = *(const float4*)&as[kk * APAD + nb + 4];
      float av[8] = {a0.x, a0.y, a0.z, a0.w, a1.x, a1.y, a1.z, a1.w};
#pragma unroll
      for (int i = 0; i < 8; ++i) {
        acc[i][0] = fmaf(av[i], wv.x, acc[i][0]);
        acc[i][1] = fmaf(av[i], wv.y, acc[i][1]);
        acc[i][2] = fmaf(av[i], wv.z, acc[i][2]);
        acc[i][3] = fmaf(av[i], wv.w, acc[i][3]);
      }
    }
    __syncthreads();
  }
#pragma unroll
  for (int i = 0; i < 8; ++i) {
    int n = n0 + nb + i;
    if (n >= N) continue;
    if (OUT_BF16) {
      bf16* out = (bf16*)out_v;
      *(uint2*)&out[(size_t)n * HF + j4] =
          make_uint2(pack_bf16(acc[i][0], acc[i][1]),
                     pack_bf16(acc[i][2], acc[i][3]));
    } else {
      float* out = (float*)out_v;
      *(float4*)&out[(size_t)n * HF + j4] =
          make_float4(acc[i][0], acc[i][1], acc[i][2], acc[i][3]);
    }
  }
}

// ============================ CSR build ====================================
__global__ __launch_bounds__(256) void hist_kernel(
    const int* __restrict__ dst, int* __restrict__ deg, int E) {
  int e = blockIdx.x * 256 + threadIdx.x;
  if (e < E) atomicAdd(&deg[dst[e]], 1);
}

__global__ __launch_bounds__(256) void scan1_kernel(
    const int* __restrict__ deg, int* __restrict__ row_ptr,
    int* __restrict__ bsum, int N) {
  const int base = blockIdx.x * 2048;
  const int tbase = base + threadIdx.x * 8;
  int vals[8];
  int tsum = 0;
#pragma unroll
  for (int i = 0; i < 8; ++i) {
    int idx = tbase + i;
    vals[i] = (idx < N) ? deg[idx] : 0;
    tsum += vals[i];
  }
  const int lane = threadIdx.x & 63, wv = threadIdx.x >> 6;
  int incl = tsum;
#pragma unroll
  for (int off = 1; off < 64; off <<= 1) {
    int nv = __shfl_up(incl, off);
    if (lane >= off) incl += nv;
  }
  __shared__ int wsum[4];
  if (lane == 63) wsum[wv] = incl;
  __syncthreads();
  int woff = 0;
  for (int w = 0; w < wv; ++w) woff += wsum[w];
  int run = woff + incl - tsum;
#pragma unroll
  for (int i = 0; i < 8; ++i) {
    int idx = tbase + i;
    if (idx < N) row_ptr[idx] = run;
    run += vals[i];
  }
  if (threadIdx.x == 255) bsum[blockIdx.x] = woff + incl;
}

__global__ __launch_bounds__(64) void scan2_kernel(
    const int* __restrict__ bsum, int* __restrict__ bpre, int NB) {
  const int lane = threadIdx.x;
  int running = 0;
  for (int c = 0; c < NB; c += 64) {
    int v = (c + lane < NB) ? bsum[c + lane] : 0;
    int incl = v;
#pragma unroll
    for (int off = 1; off < 64; off <<= 1) {
      int nv = __shfl_up(incl, off);
      if (lane >= off) incl += nv;
    }
    if (c + lane < NB) bpre[c + lane] = running + incl - v;
    running += __shfl(incl, 63);
  }
}

__global__ __launch_bounds__(256) void scan3_kernel(
    int* __restrict__ row_ptr, const int* __restrict__ bpre, int N, int E) {
  int t = blockIdx.x * 256 + threadIdx.x;
  if (t < N) row_ptr[t] += bpre[t >> 11];
  if (t == 0) row_ptr[N] = E;
}

__global__ __launch_bounds__(256) void scatter_kernel(
    const int* __restrict__ src, const int* __restrict__ dst,
    const int* __restrict__ row_ptr, int* __restrict__ cursor,
    int* __restrict__ ssorted, int E) {
  int e = blockIdx.x * 256 + threadIdx.x;
  if (e >= E) return;
  int d = dst[e];
  int pos = row_ptr[d] + atomicAdd(&cursor[d], 1);
  ssorted[pos] = src[e];
}

// ===================== attention scores ==========================
// el[n][h] = dot(feat[n][h], attn_l[h]); er likewise. 1 thread / (n,h).
__global__ __launch_bounds__(256) void scores_kernel(
    const bf16* __restrict__ feat, const float* __restrict__ attn_l,
    const float* __restrict__ attn_r, float* __restrict__ el,
    float* __restrict__ er, int N) {
  int t = blockIdx.x * 256 + threadIdx.x;
  if (t >= N * HEADS) return;
  int h = t & 3;
  const bf16x2* f2 = (const bf16x2*)(feat + (size_t)t * OUTF);
  const float* al = attn_l + h * OUTF;
  const float* ar = attn_r + h * OUTF;
  float sl = 0.f, sr = 0.f;
#pragma unroll
  for (int k = 0; k < OUTF / 2; ++k) {
    float2 v = __bfloat1622float2(f2[k]);
    sl = fmaf(v.x, al[2 * k], sl);
    sl = fmaf(v.y, al[2 * k + 1], sl);
    sr = fmaf(v.x, ar[2 * k], sr);
    sr = fmaf(v.y, ar[2 * k + 1], sr);
  }
  el[t] = sl;
  er[t] = sr;
}

// ============ fused softmax + aggregate (single edge pass) =================
// One wave per node; lane holds cols (2*lane, 2*lane+1), head h = lane>>4.
// alpha_e = exp(v_e)/sum(exp) computed without max-subtraction (bounded v).
// All 16 lanes of a head accumulate identical ssum -> no reduction needed.
// Layer 1 epilogue: B[n] = elu(inv*agg + B[n] + bias)   (in place)
__global__ __launch_bounds__(256) void agg1_fused(
    const int* __restrict__ row_ptr, const int* __restrict__ ssorted,
    const float* __restrict__ el, const float* __restrict__ er,
    const bf16* __restrict__ feat, float* __restrict__ B,
    const float* __restrict__ bias, int N) {
  int n = blockIdx.x * 4 + (threadIdx.x >> 6);
  if (n >= N) return;
  const int lane = threadIdx.x & 63;
  const int c2 = lane * 2, h = lane >> 4;
  const int rb = row_ptr[n], re = row_ptr[n + 1];
  const float ern = er[n * HEADS + h];

  float ax = 0.f, ay = 0.f, ssum = 0.f;
  int e = rb;
  for (; e + 1 < re; e += 2) {
    int s0 = ssorted[e], s1 = ssorted[e + 1];
    float x0 = __expf(lrelu(el[s0 * HEADS + h] + ern));
    float x1 = __expf(lrelu(el[s1 * HEADS + h] + ern));
    float2 f0 = unpack_bf16(*(const unsigned*)&feat[(size_t)s0 * HF + c2]);
    float2 f1 = unpack_bf16(*(const unsigned*)&feat[(size_t)s1 * HF + c2]);
    ssum += x0 + x1;
    ax = fmaf(x0, f0.x, ax); ay = fmaf(x0, f0.y, ay);
    ax = fmaf(x1, f1.x, ax); ay = fmaf(x1, f1.y, ay);
  }
  if (e < re) {
    int s = ssorted[e];
    float x = __expf(lrelu(el[s * HEADS + h] + ern));
    float2 f = unpack_bf16(*(const unsigned*)&feat[(size_t)s * HF + c2]);
    ssum += x;
    ax = fmaf(x, f.x, ax); ay = fmaf(x, f.y, ay);
  }
  float inv = 1.f / ssum;
  float2 r = *(const float2*)&B[(size_t)n * HF + c2];
  float2 bi = *(const float2*)&bias[c2];
  float vx = ax * inv + r.x + bi.x;
  float vy = ay * inv + r.y + bi.y;
  vx = (vx > 0.f) ? vx : expm1f(vx);
  vy = (vy > 0.f) ? vy : expm1f(vy);
  *(float2*)&B[(size_t)n * HF + c2] = make_float2(vx, vy);
}

// Layer 2 epilogue: head-mean -> node_feats (regs) -> sigmoid gate ->
// readout atomics (hsum/hmax per graph). No nf buffer.
__global__ __launch_bounds__(256) void agg2_fused(
    const int* __restrict__ row_ptr, const int* __restrict__ ssorted,
    const float* __restrict__ el, const float* __restrict__ er,
    const bf16* __restrict__ feat, const float* __restrict__ h1,
    const float* __restrict__ bias, const float* __restrict__ ww,
    const float* __restrict__ wb, const int* __restrict__ gids,
    float* __restrict__ hsum, unsigned* __restrict__ hmax, int N) {
  int n = blockIdx.x * 4 + (threadIdx.x >> 6);
  if (n >= N) return;
  const int lane = threadIdx.x & 63;
  const int c2 = lane * 2, h = lane >> 4;
  const int rb = row_ptr[n], re = row_ptr[n + 1];
  const float ern = er[n * HEADS + h];

  float ax = 0.f, ay = 0.f, ssum = 0.f;
  int e = rb;
  for (; e + 1 < re; e += 2) {
    int s0 = ssorted[e], s1 = ssorted[e + 1];
    float x0 = __expf(lrelu(el[s0 * HEADS + h] + ern));
    float x1 = __expf(lrelu(el[s1 * HEADS + h] + ern));
    float2 f0 = unpack_bf16(*(const unsigned*)&feat[(size_t)s0 * HF + c2]);
    float2 f1 = unpack_bf16(*(const unsigned*)&feat[(size_t)s1 * HF + c2]);
    ssum += x0 + x1;
    ax = fmaf(x0, f0.x, ax); ay = fmaf(x0, f0.y, ay);
    ax = fmaf(x1, f1.x, ax); ay = fmaf(x1, f1.y, ay);
  }
  if (e < re) {
    int s = ssorted[e];
    float x = __expf(lrelu(el[s * HEADS + h] + ern));
    float2 f = unpack_bf16(*(const unsigned*)&feat[(size_t)s * HF + c2]);
    ssum += x;
    ax = fmaf(x, f.x, ax); ay = fmaf(x, f.y, ay);
  }
  float inv = 1.f / ssum;
  float2 r = *(const float2*)&h1[(size_t)n * HF + c2];
  float2 bi = *(const float2*)&bias[c2];
  ax = ax * inv + r.x + bi.x;
  ay = ay * inv + r.y + bi.y;
  // head mean: after xor 16,32 every lane holds the sum over its 4-head class
#pragma unroll
  for (int off = 16; off < 64; off <<= 1) {
    ax += __shfl_xor(ax, off);
    ay += __shfl_xor(ay, off);
  }
  ax *= 0.25f;
  ay *= 0.25f;
  // sigmoid gate: dot(node_feats, ww) reduced over the 16-lane col groups
  int c = c2 & 31;
  float d = fmaf(ax, ww[c], ay * ww[c + 1]);
#pragma unroll
  for (int off = 1; off < 16; off <<= 1) d += __shfl_xor(d, off);
  float wv = 1.f / (1.f + __expf(-(d + wb[0])));
  if (lane < 16) {
    int g = gids[n];
    atomicAdd(&hsum[g * OUTF + c], wv * ax);
    atomicAdd(&hsum[g * OUTF + c + 1], wv * ay);
    atomicMax(&hmax[g * OUTF + c], enc_f(ax));
    atomicMax(&hmax[g * OUTF + c + 1], enc_f(ay));
  }
}

// ============================ readout tail =================================
__global__ __launch_bounds__(256) void init_readout_kernel(
    float* __restrict__ hsum, unsigned* __restrict__ hmax, int g32) {
  int t = blockIdx.x * 256 + threadIdx.x;
  if (t >= g32) return;
  hsum[t] = 0.f;
  hmax[t] = NEG_INF_ENC;
}

__global__ __launch_bounds__(256) void final_gemm_kernel(
    const float* __restrict__ hsum, const unsigned* __restrict__ hmax,
    const float* __restrict__ tw, const float* __restrict__ tb,
    float* __restrict__ out, int G) {
  __shared__ float tws[64 * PRED_DIM];
  for (int i = threadIdx.x; i < 64 * PRED_DIM; i += 256) tws[i] = tw[i];
  __syncthreads();
  int g = blockIdx.x * 2 + (threadIdx.x >> 7);
  int p = threadIdx.x & 127;
  if (g >= G) return;
  float acc = tb[p];
#pragma unroll
  for (int k = 0; k < OUTF; ++k)
    acc = fmaf(hsum[g * OUTF + k], tws[k * PRED_DIM + p], acc);
#pragma unroll
  for (int k = 0; k < OUTF; ++k)
    acc = fmaf(dec_f(hmax[g * OUTF + k]), tws[(OUTF + k) * PRED_DIM + p], acc);
  out[(size_t)g * PRED_DIM + p] = acc;
}

static inline int cdiv(long long a, int b) { return (int)((a + b - 1) / b); }

extern "C" void kernel_launch(void* const* d_in, const int* in_sizes, int n_in,
                              void* d_out, int out_size, void* d_ws,
                              size_t ws_size, hipStream_t stream) {
  const float* feats   = (const float*)d_in[0];
  const int*   src     = (const int*)d_in[1];
  const int*   dst     = (const int*)d_in[2];
  const int*   gids    = (const int*)d_in[3];
  const float* fc1_w   = (const float*)d_in[4];
  const float* attn_l1 = (const float*)d_in[5];
  const float* attn_r1 = (const float*)d_in[6];
  const float* res1_w  = (const float*)d_in[7];
  const float* bias1   = (const float*)d_in[8];
  const float* fc2_w   = (const float*)d_in[9];
  const float* attn_l2 = (const float*)d_in[10];
  const float* attn_r2 = (const float*)d_in[11];
  const float* bias2   = (const float*)d_in[12];
  const float* ww      = (const float*)d_in[13];
  const float* wb      = (const float*)d_in[14];
  const float* tw      = (const float*)d_in[15];
  const float* tb      = (const float*)d_in[16];
  float* out = (float*)d_out;

  const int N = in_sizes[0] / IN_FEATS;  // 100000
  const int E = in_sizes[1];             // 900000
  const int G = out_size / PRED_DIM;     // 2048
  const int NB = cdiv(N, 2048);

  // ---- workspace layout ----
  bf16* A = (bf16*)d_ws;                                   // N*128 bf16
  float* B  = (float*)((char*)d_ws + (size_t)N * HF * 2);  // N*128 f32
  float* el = B + (size_t)N * HF;        // N*4
  float* er = el + (size_t)N * HEADS;    // N*4
  float* hsum = er + (size_t)N * HEADS;  // G*32
  unsigned* hmax = (unsigned*)(hsum + (size_t)G * OUTF);   // G*32
  int* deg     = (int*)(hmax + (size_t)G * OUTF);  // N
  int* cursor  = deg + N;                          // N
  int* row_ptr = cursor + N;                       // N+1
  int* ssorted = row_ptr + (N + 1);                // E
  int* bsum    = ssorted + E;                      // NB
  int* bpre    = bsum + NB;                        // NB

  const int n4 = N * HEADS;
  const int gblk = cdiv(N, 64);
  const int nwblk = cdiv(N, 4);

  // ===================== CSR build =====================
  hipMemsetAsync(deg, 0, (size_t)N * sizeof(int), stream);
  hipMemsetAsync(cursor, 0, (size_t)N * sizeof(int), stream);
  hist_kernel<<<cdiv(E, 256), 256, 0, stream>>>(dst, deg, E);
  scan1_kernel<<<NB, 256, 0, stream>>>(deg, row_ptr, bsum, N);
  scan2_kernel<<<1, 64, 0, stream>>>(bsum, bpre, NB);
  scan3_kernel<<<cdiv(N, 256), 256, 0, stream>>>(row_ptr, bpre, N, E);
  scatter_kernel<<<cdiv(E, 256), 256, 0, stream>>>(src, dst, row_ptr, cursor,
                                                   ssorted, E);

  // ===================== Layer 1 =====================
  gemm_tiled<IN_FEATS, true><<<gblk, 256, 0, stream>>>(feats, fc1_w, A, N);
  gemm_tiled<IN_FEATS, false><<<gblk, 256, 0, stream>>>(feats, res1_w, B, N);
  scores_kernel<<<cdiv(n4, 256), 256, 0, stream>>>(A, attn_l1, attn_r1, el, er, N);
  agg1_fused<<<nwblk, 256, 0, stream>>>(row_ptr, ssorted, el, er, A, B, bias1, N);

  // ===================== Layer 2 =====================
  gemm_tiled<HF, true><<<gblk, 256, 0, stream>>>(B, fc2_w, A, N);
  scores_kernel<<<cdiv(n4, 256), 256, 0, stream>>>(A, attn_l2, attn_r2, el, er, N);
  init_readout_kernel<<<cdiv(G * OUTF, 256), 256, 0, stream>>>(hsum, hmax,
                                                               G * OUTF);
  agg2_fused<<<nwblk, 256, 0, stream>>>(row_ptr, ssorted, el, er, A, B, bias2,
                                        ww, wb, gids, hsum, hmax, N);

  // ===================== Readout =====================
  final_gemm_kernel<<<cdiv(G, 2), 256, 0, stream>>>(hsum, hmax, tw, tb, out, G);
}